// Round 13
// baseline (274.038 us; speedup 1.0000x reference)
//
#include <hip/hip_runtime.h>
#include <hip/hip_bf16.h>

#define NROWS   262144
#define DIN     480
#define DOUT    480

#define M_TILE  32
#define TILES   16
#define GRIDSZ  (NROWS / (M_TILE * TILES))   // 512 blocks = 2 per CU, persistent
#define XSTR    488   // ushort stride; 976B/row

#define CST_SILU 1.6765290f
#define CST_RELU 1.4142135623730951f
#define INV_S128 0.08838834764831845f
#define INV_S64  0.125f
#define INV_S32  0.17677669529663687f

// ws fragment layout (bf16x8 per lane, 1024B per fragment), r5 semantics (unscaled):
//   W0 tile t(0..13) kk(0..3) -> t*4+kk (0..55); W1 jt,kk -> 56+jt*2+kk; W2 tu -> 64+tu
#define WS_FRAGS 66
#define WS_BYTES (WS_FRAGS * 64 * 16)

typedef short bf16x8 __attribute__((ext_vector_type(8)));
typedef float f32x4  __attribute__((ext_vector_type(4)));

__device__ __forceinline__ ushort f2bf(float f) {
    unsigned u = __float_as_uint(f);
    u = (u + 0x7FFFu + ((u >> 16) & 1u)) >> 16;   // RNE
    return (ushort)u;
}
__device__ __forceinline__ unsigned pk2(float a, float b) {
    __hip_bfloat162 h = __float22bfloat162_rn(float2{a, b});
    return *reinterpret_cast<unsigned*>(&h);
}

__device__ __forceinline__ bf16x8 load_b_frag(const float* __restrict__ W, int ldw,
                                              int kbase, int nbase, int lane) {
    int n  = nbase + (lane & 15);
    int k0 = kbase + ((lane >> 4) << 3);
    bf16x8 f;
#pragma unroll
    for (int e = 0; e < 8; ++e) f[e] = (short)f2bf(W[(k0 + e) * ldw + n]);
    return f;
}

__global__ __launch_bounds__(64) void prep_frags(
        const float* __restrict__ W0, const float* __restrict__ W1,
        const float* __restrict__ W2, ushort* __restrict__ ws) {
    const int b = blockIdx.x, lane = threadIdx.x;
    const int lr = lane & 15, kg = lane >> 4;
    const float* W; int ldw, n, k0;
    if (b < 56)      { W = W0; ldw = 224; n = (b >> 2) * 16 + lr; k0 = (b & 3) * 32 + (kg << 3); }
    else if (b < 64) { int t = b - 56; W = W1; ldw = 64; n = (t >> 1) * 16 + lr; k0 = (t & 1) * 32 + (kg << 3); }
    else             { W = W2; ldw = 32; n = (b - 64) * 16 + lr; k0 = (kg << 3); }
    bf16x8 f;
#pragma unroll
    for (int e = 0; e < 8; ++e) f[e] = (short)f2bf(W[(k0 + e) * ldw + n]);
    *reinterpret_cast<bf16x8*>(ws + (b * 64 + lane) * 8) = f;
}

// Producer/consumer wave specialization: wave 3 stages tile t+1 into the other
// half of a double-buffered LDS while waves 0-2 compute tile t. Producer's
// in-flight registers live only inside its own loop -> no cross-phase spill
// (the failure mode of r8/r9). 2 blocks/CU, one barrier per tile.
template <bool PRE>
__global__ __launch_bounds__(256, 2) void percep_kernel(
        const float* __restrict__ x,  const float* __restrict__ W0,
        const float* __restrict__ bias0, const float* __restrict__ W1,
        const float* __restrict__ W2, float* __restrict__ out,
        const ushort* __restrict__ ws) {
    __shared__ __align__(16) ushort xs[2][M_TILE * XSTR];   // 62464 B (<64KB static cap)

    const int tid  = threadIdx.x;
    const int lane = tid & 63;
    const int wid  = tid >> 6;
    const int lr   = lane & 15;
    const int kg   = lane >> 4;
    const int blk_row0 = blockIdx.x * (M_TILE * TILES);
    const bf16x8* F = reinterpret_cast<const bf16x8*>(ws);

    // ---------------- producer: stage 32x480 f32 -> bf16 deinterleaved ----------------
    // Same mapping as r5 (256-thread staging), executed by one wave in 4 sub-passes
    // (vt = sub*64+lane plays the role of r5's tid). 15 float4 live per sub-pass.
    auto stage = [&](int buf, int row0) {
        ushort* bb = xs[buf];
#pragma unroll 1
        for (int sub = 0; sub < 4; ++sub) {
            const int vt = (sub << 6) + lane;
            const int rA = vt >> 5, cA = vt & 31;     // region 0: 4 rows (stride 8)
            const int rB = vt >> 4, gB = vt & 15;     // region 1: 2 rows (stride 16)
            const int rC = vt >> 3, gC = vt & 7;      // region 2: 1 row
            float4 a0, a1, a2, a3, b0, b1, b2, b3, b4, b5, c0, c1, c2, c3, c4;
            a0 = reinterpret_cast<const float4*>(x + (row0 + rA     ) * DIN)[cA];
            a1 = reinterpret_cast<const float4*>(x + (row0 + rA +  8) * DIN)[cA];
            a2 = reinterpret_cast<const float4*>(x + (row0 + rA + 16) * DIN)[cA];
            a3 = reinterpret_cast<const float4*>(x + (row0 + rA + 24) * DIN)[cA];
            { const float4* p = reinterpret_cast<const float4*>(x + (row0 + rB) * DIN + 128 + 12 * gB);
              b0 = p[0]; b1 = p[1]; b2 = p[2]; }
            { const float4* p = reinterpret_cast<const float4*>(x + (row0 + rB + 16) * DIN + 128 + 12 * gB);
              b3 = p[0]; b4 = p[1]; b5 = p[2]; }
            { const float4* p = reinterpret_cast<const float4*>(x + (row0 + rC) * DIN + 320 + 20 * gC);
              c0 = p[0]; c1 = p[1]; c2 = p[2]; c3 = p[3]; c4 = p[4]; }

            // region 0: straight copy, cols 0..127
            { uint2 o = { pk2(a0.x, a0.y), pk2(a0.z, a0.w) };
              *reinterpret_cast<uint2*>(&bb[(rA     ) * XSTR + cA * 4]) = o; }
            { uint2 o = { pk2(a1.x, a1.y), pk2(a1.z, a1.w) };
              *reinterpret_cast<uint2*>(&bb[(rA +  8) * XSTR + cA * 4]) = o; }
            { uint2 o = { pk2(a2.x, a2.y), pk2(a2.z, a2.w) };
              *reinterpret_cast<uint2*>(&bb[(rA + 16) * XSTR + cA * 4]) = o; }
            { uint2 o = { pk2(a3.x, a3.y), pk2(a3.z, a3.w) };
              *reinterpret_cast<uint2*>(&bb[(rA + 24) * XSTR + cA * 4]) = o; }
            // region 1: x1[n,i,m]=x[n,128+3i+m] -> col 128+64m+i
            { float v[12] = { b0.x, b0.y, b0.z, b0.w, b1.x, b1.y, b1.z, b1.w, b2.x, b2.y, b2.z, b2.w };
#pragma unroll
              for (int m = 0; m < 3; ++m) {
                  uint2 o = { pk2(v[m], v[m + 3]), pk2(v[m + 6], v[m + 9]) };
                  *reinterpret_cast<uint2*>(&bb[rB * XSTR + 128 + 64 * m + 4 * gB]) = o;
              } }
            { float v[12] = { b3.x, b3.y, b3.z, b3.w, b4.x, b4.y, b4.z, b4.w, b5.x, b5.y, b5.z, b5.w };
#pragma unroll
              for (int m = 0; m < 3; ++m) {
                  uint2 o = { pk2(v[m], v[m + 3]), pk2(v[m + 6], v[m + 9]) };
                  *reinterpret_cast<uint2*>(&bb[(rB + 16) * XSTR + 128 + 64 * m + 4 * gB]) = o;
              } }
            // region 2: x2[n,i,m]=x[n,320+5i+m] -> col 320+32m+i
            { float v[20] = { c0.x, c0.y, c0.z, c0.w, c1.x, c1.y, c1.z, c1.w, c2.x, c2.y, c2.z, c2.w,
                              c3.x, c3.y, c3.z, c3.w, c4.x, c4.y, c4.z, c4.w };
#pragma unroll
              for (int m = 0; m < 5; ++m) {
                  uint2 o = { pk2(v[m], v[m + 5]), pk2(v[m + 10], v[m + 15]) };
                  *reinterpret_cast<uint2*>(&bb[rC * XSTR + 320 + 32 * m + 4 * gC]) = o;
              } }
        }
    };

    // ---------------- consumers: r5 compute, split across 3 waves, both row panels ----------------
    auto compute = [&](int buf, int row0) {
        const ushort* bb = xs[buf];
        bf16x8 aS[2][4];
#pragma unroll
        for (int rf = 0; rf < 2; ++rf)
#pragma unroll
            for (int kk = 0; kk < 4; ++kk)
                aS[rf][kk] = *reinterpret_cast<const bf16x8*>(
                    &bb[(rf * 16 + lr) * XSTR + kk * 32 + (kg << 3)]);

        auto s_acc = [&](int st, int rf) -> f32x4 {
            f32x4 acc = { 0.f, 0.f, 0.f, 0.f };
#pragma unroll
            for (int kk = 0; kk < 4; ++kk) {
                bf16x8 b = PRE ? F[(st * 4 + kk) * 64 + lane]
                               : load_b_frag(W0, 224, kk * 32, st * 16, lane);
                acc = __builtin_amdgcn_mfma_f32_16x16x32_bf16(aS[rf][kk], b, acc, 0, 0, 0);
            }
            return acc;
        };
        auto gate_tile = [&](int st, int rf) -> f32x4 {
            f32x4 acc = s_acc(st, rf);
            float bias = bias0[st * 16 + lr];
            f32x4 g;
#pragma unroll
            for (int r = 0; r < 4; ++r) {
                float s = acc[r] * INV_S128 + bias;
                g[r] = fmaxf(s, 0.f) * CST_RELU;
            }
            return g;
        };
        auto silu_tile = [&](int st, int rf) {
            f32x4 acc = s_acc(st, rf);
            float bias = bias0[st * 16 + lr];
            int orow = row0 + rf * 16 + (kg << 2);
#pragma unroll
            for (int r = 0; r < 4; ++r) {
                float s = acc[r] * INV_S128 + bias;
                float val = CST_SILU * s * __builtin_amdgcn_rcpf(1.f + __expf(-s));
                out[(orow + r) * DOUT + st * 16 + lr] = val;
            }
        };
        auto v_tile = [&](int jtg, int rf, f32x4 g) {
            f32x4 a0 = {0,0,0,0}, a1 = {0,0,0,0}, a2 = {0,0,0,0};
#pragma unroll
            for (int kk = 0; kk < 2; ++kk) {
                bf16x8 b = PRE ? F[(56 + jtg * 2 + kk) * 64 + lane]
                               : load_b_frag(W1, 64, kk * 32, jtg * 16, lane);
                const ushort* base = &bb[(rf * 16 + lr) * XSTR + 128 + kk * 32 + (kg << 3)];
                a0 = __builtin_amdgcn_mfma_f32_16x16x32_bf16(*reinterpret_cast<const bf16x8*>(base +   0), b, a0, 0, 0, 0);
                a1 = __builtin_amdgcn_mfma_f32_16x16x32_bf16(*reinterpret_cast<const bf16x8*>(base +  64), b, a1, 0, 0, 0);
                a2 = __builtin_amdgcn_mfma_f32_16x16x32_bf16(*reinterpret_cast<const bf16x8*>(base + 128), b, a2, 0, 0, 0);
            }
            int j = jtg * 16 + lr;
            int orow = row0 + rf * 16 + (kg << 2);
#pragma unroll
            for (int r = 0; r < 4; ++r) {
                float gg = g[r] * INV_S64;
                float* po = out + (orow + r) * DOUT + 128 + 3 * j;
                po[0] = a0[r] * gg; po[1] = a1[r] * gg; po[2] = a2[r] * gg;
            }
        };
        auto t_tile = [&](int tu, int rf, f32x4 g) {
            bf16x8 bt = PRE ? F[(64 + tu) * 64 + lane]
                            : load_b_frag(W2, 32, 0, tu * 16, lane);
            const ushort* base = &bb[(rf * 16 + lr) * XSTR + 320 + (kg << 3)];
            f32x4 z = {0,0,0,0};
            f32x4 a0 = __builtin_amdgcn_mfma_f32_16x16x32_bf16(*reinterpret_cast<const bf16x8*>(base +   0), bt, z, 0, 0, 0);
            f32x4 a1 = __builtin_amdgcn_mfma_f32_16x16x32_bf16(*reinterpret_cast<const bf16x8*>(base +  32), bt, z, 0, 0, 0);
            f32x4 a2 = __builtin_amdgcn_mfma_f32_16x16x32_bf16(*reinterpret_cast<const bf16x8*>(base +  64), bt, z, 0, 0, 0);
            f32x4 a3 = __builtin_amdgcn_mfma_f32_16x16x32_bf16(*reinterpret_cast<const bf16x8*>(base +  96), bt, z, 0, 0, 0);
            f32x4 a4 = __builtin_amdgcn_mfma_f32_16x16x32_bf16(*reinterpret_cast<const bf16x8*>(base + 128), bt, z, 0, 0, 0);
            int j = tu * 16 + lr;
            int orow = row0 + rf * 16 + (kg << 2);
#pragma unroll
            for (int r = 0; r < 4; ++r) {
                float gg = g[r] * INV_S32;
                float* po = out + (orow + r) * DOUT + 320 + 5 * j;
                po[0] = a0[r] * gg; po[1] = a1[r] * gg; po[2] = a2[r] * gg;
                po[3] = a3[r] * gg; po[4] = a4[r] * gg;
            }
        };

        if (wid < 2) {
            // c0: gates 8,9 -> V 0,1 ; silu 0,1.  c1: gates 10,11 -> V 2,3 ; silu 2,3.
            const int c = wid;
#pragma unroll
            for (int rf = 0; rf < 2; ++rf) { f32x4 g = gate_tile(8 + 2 * c, rf); v_tile(2 * c, rf, g); }
#pragma unroll
            for (int rf = 0; rf < 2; ++rf) silu_tile(2 * c, rf);
#pragma unroll
            for (int rf = 0; rf < 2; ++rf) { f32x4 g = gate_tile(9 + 2 * c, rf); v_tile(2 * c + 1, rf, g); }
#pragma unroll
            for (int rf = 0; rf < 2; ++rf) silu_tile(2 * c + 1, rf);
        } else {
            // c2: gates 12,13 -> T 0,1 ; silu 4..7
#pragma unroll
            for (int rf = 0; rf < 2; ++rf) { f32x4 g = gate_tile(12, rf); t_tile(0, rf, g); }
#pragma unroll
            for (int rf = 0; rf < 2; ++rf) silu_tile(4, rf);
#pragma unroll
            for (int rf = 0; rf < 2; ++rf) { f32x4 g = gate_tile(13, rf); t_tile(1, rf, g); }
#pragma unroll
            for (int rf = 0; rf < 2; ++rf) silu_tile(5, rf);
#pragma unroll
            for (int rf = 0; rf < 2; ++rf) silu_tile(6, rf);
#pragma unroll
            for (int rf = 0; rf < 2; ++rf) silu_tile(7, rf);
        }
    };

    // ---------------- tile loop: P stages t+1 while C computes t ----------------
    if (wid == 3) stage(0, blk_row0);
    __syncthreads();
#pragma unroll 1
    for (int t = 0; t < TILES; ++t) {
        if (wid == 3) {
            if (t + 1 < TILES) stage((t + 1) & 1, blk_row0 + (t + 1) * M_TILE);
        } else {
            compute(t & 1, blk_row0 + t * M_TILE);
        }
        __syncthreads();
    }
}

extern "C" void kernel_launch(void* const* d_in, const int* in_sizes, int n_in,
                              void* d_out, int out_size, void* d_ws, size_t ws_size,
                              hipStream_t stream) {
    const float* x  = (const float*)d_in[0];
    const float* W0 = (const float*)d_in[1];
    const float* b0 = (const float*)d_in[2];
    const float* W1 = (const float*)d_in[3];
    const float* W2 = (const float*)d_in[4];
    float* out = (float*)d_out;
    dim3 grid(GRIDSZ), block(256);
    if (ws_size >= WS_BYTES) {
        hipLaunchKernelGGL(prep_frags, dim3(WS_FRAGS), dim3(64), 0, stream, W0, W1, W2, (ushort*)d_ws);
        hipLaunchKernelGGL((percep_kernel<true>), grid, block, 0, stream,
                           x, W0, b0, W1, W2, out, (const ushort*)d_ws);
    } else {
        hipLaunchKernelGGL((percep_kernel<false>), grid, block, 0, stream,
                           x, W0, b0, W1, W2, out, (const ushort*)d_ws);
    }
}